// Round 9
// baseline (84.743 us; speedup 1.0000x reference)
//
#include <hip/hip_runtime.h>
#include <hip/hip_bf16.h>
#include <hip/hip_fp16.h>

#define BDIM    128   // batch size, fixed by problem
#define NGROUPS 2     // batch groups (64 batches each), one per XCD quad
#define GCOLS   64    // batch columns per group
#define ROWB    (GCOLS * 2)            // bytes per xTh row = 128 (one L2 line)
#define EBLK    2048  // edge-kernel blocks (divisible by 8)
#define RANKS   (EBLK / NGROUPS)       // blocks per group = 1024
#define CHUNK   256   // edges staged in LDS per block iteration
#define S1BLK   (NGROUPS * 8)          // stage-1 edge-reduce blocks = 16
#define HBLK2   8     // stage-1 h-reduce blocks
#define RPS     (RANKS / 8)            // ranks per stage-1 block = 128

// ---------------------------------------------------------------------------
// Kernel 1: transpose+convert x (B=128,N) f32 -> xTh[g][N][64] fp16 slices,
// FUSED with h-term partials: hp[block][b] = sum_{n in tile} x[b,n]*h[n].
// Slice g holds batches [64g,64g+64): 6.4MB per XCD quad; 128B-aligned rows.
// ---------------------------------------------------------------------------
__global__ __launch_bounds__(256) void transpose_h_kernel(
    const float* __restrict__ x, const float* __restrict__ h,
    __half* __restrict__ xTh, float* __restrict__ hp, int N) {
  __shared__ float tile[64][BDIM + 1];
  __shared__ float sh[64];
  __shared__ float red2[2][BDIM];
  const int tid = threadIdx.x;
  const int n0  = blockIdx.x * 64;

  const int tn  = tid & 63;
  const int tb0 = tid >> 6;
  const int n   = n0 + tn;
  if (n < N) {
    for (int b = tb0; b < BDIM; b += 4) tile[tn][b] = x[(size_t)b * N + n];
  } else {
    for (int b = tb0; b < BDIM; b += 4) tile[tn][b] = 0.f;
  }
  if (tid < 64) sh[tid] = (n0 + tid < N) ? h[n0 + tid] : 0.f;
  __syncthreads();

  // h-term partial: thread (half, b) sums 32 n's
  const int hb   = tid & 127;
  const int half = tid >> 7;
  float hacc = 0.f;
#pragma unroll
  for (int m = 0; m < 32; ++m) {
    const int nl = half * 32 + m;
    hacc += tile[nl][hb] * sh[nl];
  }
  red2[half][hb] = hacc;

  // transpose store: thread = (k, g2, c2); 32 lanes write 128B contiguous
  const int c2 = tid & 31;
  const int g2 = (tid >> 5) & 1;
  const int k  = tid >> 6;
  for (int it = 0; it < 16; ++it) {
    const int nl = it * 4 + k;
    if (n0 + nl < N) {
      const float a = tile[nl][g2 * GCOLS + 2 * c2];
      const float b = tile[nl][g2 * GCOLS + 2 * c2 + 1];
      __half2* dst = (__half2*)(xTh + ((size_t)g2 * N + (n0 + nl)) * GCOLS + 2 * c2);
      *dst = __floats2half2_rn(a, b);
    }
  }
  __syncthreads();
  if (tid < BDIM) hp[(size_t)blockIdx.x * BDIM + tid] = red2[0][tid] + red2[1][tid];
}

// ---------------------------------------------------------------------------
// 8-column fp16 product with v_fma_mix_f32 accumulate.
// ---------------------------------------------------------------------------
__device__ __forceinline__ void fma8mix(float* acc, int4 vi, int4 vj, float Jv) {
  const int wi[4] = {vi.x, vi.y, vi.z, vi.w};
  const int wj[4] = {vj.x, vj.y, vj.z, vj.w};
#pragma unroll
  for (int w = 0; w < 4; ++w) {
    const __half2 hi = __builtin_bit_cast(__half2, wi[w]);
    const __half2 hj = __builtin_bit_cast(__half2, wj[w]);
    const int p = __builtin_bit_cast(int, __hmul2(hi, hj));
    asm("v_fma_mix_f32 %0, %1, %2, %0 op_sel_hi:[1,0,0]"
        : "+v"(acc[2 * w]) : "v"(p), "v"(Jv));
    asm("v_fma_mix_f32 %0, %1, %2, %0 op_sel:[1,0,0] op_sel_hi:[1,0,0]"
        : "+v"(acc[2 * w + 1]) : "v"(p), "v"(Jv));
  }
}

// ---------------------------------------------------------------------------
// Kernel 2: edge interactions. 8 lanes per edge, 16B/lane of a 128B row ->
// one aligned L2 line per row access. 4-wide independent gathers per step
// (8 int4 loads in flight before any consume) + __launch_bounds__(256,4)
// (VGPR cap 128) to keep them register-resident: MLP ~8 lines/wave.
// Rank r owns chunks [r*TC/RANKS, (r+1)*TC/RANKS) -> only the globally-last
// chunk is padded (J=0). Block -> (group, rank): g=(blockIdx&7)>>2 -> XCD
// quad; 6.4MB slice L2-quad-resident.
// ---------------------------------------------------------------------------
__global__ __launch_bounds__(256, 4) void edge_kernel(
    const __half* __restrict__ xTh, const float* __restrict__ J,
    const int* __restrict__ ei, const int* __restrict__ ej,
    float* __restrict__ P, int E, int N) {
  const int tid  = threadIdx.x;
  const int g    = (blockIdx.x & 7) >> 2;
  const int rank = (blockIdx.x >> 3) * 4 + (blockIdx.x & 3);
  const int wave = tid >> 6;
  const int lane = tid & 63;
  const int k    = lane >> 3;          // edge sub-index 0..7
  const char* xgl = (const char*)xTh + (size_t)g * N * ROWB + (lane & 7) * 16;

  const int TC    = (E + CHUNK - 1) / CHUNK;  // total chunks
  const int start = (int)(((long)rank * TC / RANKS)) * CHUNK;
  const int end   = min((int)(((long)(rank + 1) * TC / RANKS)) * CHUNK, E);

  __shared__ int4 se[CHUNK];

  // register prefetch of first chunk (issue early, write late)
  int ri = 0, rj = 0;
  float rJ = 0.f;
  {
    const int e = start + tid;
    if (e < end) { ri = ei[e]; rj = ej[e]; rJ = J[e]; }
  }

  float acc[8] = {0.f, 0.f, 0.f, 0.f, 0.f, 0.f, 0.f, 0.f};

  for (int base = start; base < end; base += CHUNK) {
    se[tid] = make_int4(ri, rj, __float_as_int(rJ), 0);
    __syncthreads();

    // issue next chunk's loads; latency hides under the gather loop
    {
      const int e = base + CHUNK + tid;
      ri = 0; rj = 0; rJ = 0.f;
      if (e < end) { ri = ei[e]; rj = ej[e]; rJ = J[e]; }
    }

    const int lbase = wave * 64 + k;
#pragma unroll
    for (int u = 0; u < 8; u += 4) {
      const int4 e0 = se[lbase + (u + 0) * 8];
      const int4 e1 = se[lbase + (u + 1) * 8];
      const int4 e2 = se[lbase + (u + 2) * 8];
      const int4 e3 = se[lbase + (u + 3) * 8];
      const int4 vi0 = *(const int4*)(xgl + (unsigned)e0.x * ROWB);
      const int4 vj0 = *(const int4*)(xgl + (unsigned)e0.y * ROWB);
      const int4 vi1 = *(const int4*)(xgl + (unsigned)e1.x * ROWB);
      const int4 vj1 = *(const int4*)(xgl + (unsigned)e1.y * ROWB);
      const int4 vi2 = *(const int4*)(xgl + (unsigned)e2.x * ROWB);
      const int4 vj2 = *(const int4*)(xgl + (unsigned)e2.y * ROWB);
      const int4 vi3 = *(const int4*)(xgl + (unsigned)e3.x * ROWB);
      const int4 vj3 = *(const int4*)(xgl + (unsigned)e3.y * ROWB);
      fma8mix(acc, vi0, vj0, __int_as_float(e0.z));
      fma8mix(acc, vi1, vj1, __int_as_float(e1.z));
      fma8mix(acc, vi2, vj2, __int_as_float(e2.z));
      fma8mix(acc, vi3, vj3, __int_as_float(e3.z));
    }
    __syncthreads();
  }

  // combine the 8 k-lanes sharing each column eighth (xor 8,16,32)
#pragma unroll
  for (int off = 8; off < 64; off <<= 1)
#pragma unroll
    for (int w = 0; w < 8; ++w) acc[w] += __shfl_xor(acc[w], off);

  __shared__ float red[4][GCOLS];
  if (lane < 8)
#pragma unroll
    for (int w = 0; w < 8; ++w) red[wave][lane * 8 + w] = acc[w];
  __syncthreads();
  if (tid < GCOLS) {
    const float s = red[0][tid] + red[1][tid] + red[2][tid] + red[3][tid];
    P[((size_t)g * RANKS + rank) * GCOLS + tid] = s;
  }
}

// ---------------------------------------------------------------------------
// Kernel 3: stage-1 reduce. Blocks [0,16): edge partials (g,s) sum 128 rank
// rows -> P2. Blocks [16,24): h partials, block s sums rows r%8==s -> hp2.
// ---------------------------------------------------------------------------
__global__ __launch_bounds__(256) void reduce1_kernel(
    const float* __restrict__ P, const float* __restrict__ hp,
    float* __restrict__ P2, float* __restrict__ hp2, int hrows) {
  __shared__ float red[4][GCOLS];
  __shared__ float redh[2][BDIM];
  if (blockIdx.x < S1BLK) {
    const int g  = blockIdx.x >> 3;
    const int s  = blockIdx.x & 7;
    const int rl = threadIdx.x >> 6;  // 0..3
    const int c  = threadIdx.x & 63;
    float acc = 0.f;
    for (int rr = rl; rr < RPS; rr += 4)
      acc += P[((size_t)g * RANKS + s * RPS + rr) * GCOLS + c];
    red[rl][c] = acc;
    __syncthreads();
    if (threadIdx.x < GCOLS) {
      float sum = 0.f;
      for (int r = 0; r < 4; ++r) sum += red[r][threadIdx.x];
      P2[(size_t)blockIdx.x * GCOLS + threadIdx.x] = sum;
    }
  } else {
    const int s  = blockIdx.x - S1BLK;   // 0..7
    const int b  = threadIdx.x & 127;
    const int rg = threadIdx.x >> 7;
    float acc = 0.f;
    for (int r = s + 8 * rg; r < hrows; r += 16)
      acc += hp[(size_t)r * BDIM + b];
    redh[rg][b] = acc;
    __syncthreads();
    if (threadIdx.x < BDIM)
      hp2[(size_t)s * BDIM + threadIdx.x] = redh[0][threadIdx.x] + redh[1][threadIdx.x];
  }
}

// ---------------------------------------------------------------------------
// Kernel 4: final: out[b] = sum_s hp2[s][b] + sum_s P2[(g*8+s)][c].
// ---------------------------------------------------------------------------
__global__ __launch_bounds__(128) void reduce2_kernel(
    const float* __restrict__ P2, const float* __restrict__ hp2,
    float* __restrict__ out) {
  const int b = threadIdx.x;
  const int g = b >> 6;
  const int c = b & 63;
  float acc = 0.f;
  for (int s = 0; s < 8; ++s) acc += hp2[(size_t)s * BDIM + b];
  for (int s = 0; s < 8; ++s) acc += P2[(size_t)(g * 8 + s) * GCOLS + c];
  out[b] = acc;
}

extern "C" void kernel_launch(void* const* d_in, const int* in_sizes, int n_in,
                              void* d_out, int out_size, void* d_ws, size_t ws_size,
                              hipStream_t stream) {
  const float* x  = (const float*)d_in[0];
  const float* h  = (const float*)d_in[1];
  const float* J  = (const float*)d_in[2];
  const int*   ei = (const int*)d_in[3];
  const int*   ej = (const int*)d_in[4];
  float* out = (float*)d_out;

  const int N = in_sizes[1];   // 50000
  const int E = in_sizes[2];   // 1600000

  const int tblocks = (N + 63) / 64;

  // ws layout: xTh (2*N*64 halves) | P (2048*64) | P2 (16*64) | hp (tblocks*128) | hp2 (8*128)
  __half* xTh = (__half*)d_ws;
  float* P   = (float*)(xTh + (size_t)NGROUPS * N * GCOLS);
  float* P2  = P   + (size_t)NGROUPS * RANKS * GCOLS;
  float* hp  = P2  + (size_t)S1BLK * GCOLS;
  float* hp2 = hp  + (size_t)tblocks * BDIM;

  // 1) transpose + fp16 convert + h-term partials
  transpose_h_kernel<<<tblocks, 256, 0, stream>>>(x, h, xTh, hp, N);

  // 2) edge interactions (2 groups, XCD-quad affine, 128B lines, 8-deep MLP)
  edge_kernel<<<EBLK, 256, 0, stream>>>(xTh, J, ei, ej, P, E, N);

  // 3) stage-1 reduce (edge partials + h partials)
  reduce1_kernel<<<S1BLK + HBLK2, 256, 0, stream>>>(P, hp, P2, hp2, tblocks);

  // 4) final deterministic reduce (overwrites d_out)
  reduce2_kernel<<<1, BDIM, 0, stream>>>(P2, hp2, out);
}

// Round 10
// 81.314 us; speedup vs baseline: 1.0422x; 1.0422x over previous
//
#include <hip/hip_runtime.h>
#include <hip/hip_bf16.h>
#include <hip/hip_fp16.h>

#define BDIM    128   // batch size, fixed by problem
#define NGROUPS 2     // batch groups (64 batches each), one per XCD quad
#define GCOLS   64    // batch columns per group
#define ROWB    (GCOLS * 2)            // bytes per xTh row = 128 (one L2 line)
#define EBLK    2048  // edge-kernel blocks (divisible by 8)
#define RANKS   (EBLK / NGROUPS)       // blocks per group = 1024
#define CHUNK   256   // edges staged in LDS per block iteration
#define S1BLK   (NGROUPS * 8)          // stage-1 edge-reduce blocks = 16
#define HBLK2   8     // stage-1 h-reduce blocks
#define RPS     (RANKS / 8)            // ranks per stage-1 block = 128

// ---------------------------------------------------------------------------
// Kernel 1: transpose+convert x (B=128,N) f32 -> xTh[g][N][64] fp16 slices,
// FUSED with h-term partials: hp[block][b] = sum_{n in tile} x[b,n]*h[n].
// Slice g holds batches [64g,64g+64): 6.4MB per XCD quad; 128B-aligned rows.
// ---------------------------------------------------------------------------
__global__ __launch_bounds__(256) void transpose_h_kernel(
    const float* __restrict__ x, const float* __restrict__ h,
    __half* __restrict__ xTh, float* __restrict__ hp, int N) {
  __shared__ float tile[64][BDIM + 1];
  __shared__ float sh[64];
  __shared__ float red2[2][BDIM];
  const int tid = threadIdx.x;
  const int n0  = blockIdx.x * 64;

  const int tn  = tid & 63;
  const int tb0 = tid >> 6;
  const int n   = n0 + tn;
  if (n < N) {
    for (int b = tb0; b < BDIM; b += 4) tile[tn][b] = x[(size_t)b * N + n];
  } else {
    for (int b = tb0; b < BDIM; b += 4) tile[tn][b] = 0.f;
  }
  if (tid < 64) sh[tid] = (n0 + tid < N) ? h[n0 + tid] : 0.f;
  __syncthreads();

  // h-term partial: thread (half, b) sums 32 n's
  const int hb   = tid & 127;
  const int half = tid >> 7;
  float hacc = 0.f;
#pragma unroll
  for (int m = 0; m < 32; ++m) {
    const int nl = half * 32 + m;
    hacc += tile[nl][hb] * sh[nl];
  }
  red2[half][hb] = hacc;

  // transpose store: thread = (k, g2, c2); 32 lanes write 128B contiguous
  const int c2 = tid & 31;
  const int g2 = (tid >> 5) & 1;
  const int k  = tid >> 6;
  for (int it = 0; it < 16; ++it) {
    const int nl = it * 4 + k;
    if (n0 + nl < N) {
      const float a = tile[nl][g2 * GCOLS + 2 * c2];
      const float b = tile[nl][g2 * GCOLS + 2 * c2 + 1];
      __half2* dst = (__half2*)(xTh + ((size_t)g2 * N + (n0 + nl)) * GCOLS + 2 * c2);
      *dst = __floats2half2_rn(a, b);
    }
  }
  __syncthreads();
  if (tid < BDIM) hp[(size_t)blockIdx.x * BDIM + tid] = red2[0][tid] + red2[1][tid];
}

// ---------------------------------------------------------------------------
// 8-column fp16 product with v_fma_mix_f32 accumulate.
// ---------------------------------------------------------------------------
__device__ __forceinline__ void fma8mix(float* acc, int4 vi, int4 vj, float Jv) {
  const int wi[4] = {vi.x, vi.y, vi.z, vi.w};
  const int wj[4] = {vj.x, vj.y, vj.z, vj.w};
#pragma unroll
  for (int w = 0; w < 4; ++w) {
    const __half2 hi = __builtin_bit_cast(__half2, wi[w]);
    const __half2 hj = __builtin_bit_cast(__half2, wj[w]);
    const int p = __builtin_bit_cast(int, __hmul2(hi, hj));
    asm("v_fma_mix_f32 %0, %1, %2, %0 op_sel_hi:[1,0,0]"
        : "+v"(acc[2 * w]) : "v"(p), "v"(Jv));
    asm("v_fma_mix_f32 %0, %1, %2, %0 op_sel:[1,0,0] op_sel_hi:[1,0,0]"
        : "+v"(acc[2 * w + 1]) : "v"(p), "v"(Jv));
  }
}

// ---------------------------------------------------------------------------
// Kernel 2: edge interactions. 8 lanes per edge, 16B/lane of a 128B row ->
// one aligned L2 line per row access. Per chunk-step ALL 16 row gathers
// (8 edges) are issued as one cluster, pinned by sched_barrier(0) before
// the consume cluster -> 16 lines in flight per wave (vs ~2 when the
// compiler serializes; VGPR_Count is the tell). Rank r owns chunks
// [r*TC/RANKS,(r+1)*TC/RANKS). Block -> (group, rank): g=(blockIdx&7)>>2
// -> XCD quad; 6.4MB slice quad-L2-resident.
// ---------------------------------------------------------------------------
__global__ __launch_bounds__(256, 4) void edge_kernel(
    const __half* __restrict__ xTh, const float* __restrict__ J,
    const int* __restrict__ ei, const int* __restrict__ ej,
    float* __restrict__ P, int E, int N) {
  const int tid  = threadIdx.x;
  const int g    = (blockIdx.x & 7) >> 2;
  const int rank = (blockIdx.x >> 3) * 4 + (blockIdx.x & 3);
  const int wave = tid >> 6;
  const int lane = tid & 63;
  const int k    = lane >> 3;          // edge sub-index 0..7
  const char* xgl = (const char*)xTh + (size_t)g * N * ROWB + (lane & 7) * 16;

  const int TC    = (E + CHUNK - 1) / CHUNK;  // total chunks
  const int start = (int)(((long)rank * TC / RANKS)) * CHUNK;
  const int end   = min((int)(((long)(rank + 1) * TC / RANKS)) * CHUNK, E);

  __shared__ int4 se[CHUNK];

  // register prefetch of first chunk (issue early, write late)
  int ri = 0, rj = 0;
  float rJ = 0.f;
  {
    const int e = start + tid;
    if (e < end) { ri = ei[e]; rj = ej[e]; rJ = J[e]; }
  }

  float acc[8] = {0.f, 0.f, 0.f, 0.f, 0.f, 0.f, 0.f, 0.f};

  for (int base = start; base < end; base += CHUNK) {
    se[tid] = make_int4(ri, rj, __float_as_int(rJ), 0);
    __syncthreads();

    // issue next chunk's index loads; latency hides under this whole chunk
    {
      const int e = base + CHUNK + tid;
      ri = 0; rj = 0; rJ = 0.f;
      if (e < end) { ri = ei[e]; rj = ej[e]; rJ = J[e]; }
    }

    const int lbase = wave * 64 + k;
    // ---- issue cluster: 8 LDS descriptor reads + 16 row gathers ----
    const int4 eA0 = se[lbase + 0 * 8];
    const int4 eA1 = se[lbase + 1 * 8];
    const int4 eA2 = se[lbase + 2 * 8];
    const int4 eA3 = se[lbase + 3 * 8];
    const int4 viA0 = *(const int4*)(xgl + (unsigned)eA0.x * ROWB);
    const int4 vjA0 = *(const int4*)(xgl + (unsigned)eA0.y * ROWB);
    const int4 viA1 = *(const int4*)(xgl + (unsigned)eA1.x * ROWB);
    const int4 vjA1 = *(const int4*)(xgl + (unsigned)eA1.y * ROWB);
    const int4 viA2 = *(const int4*)(xgl + (unsigned)eA2.x * ROWB);
    const int4 vjA2 = *(const int4*)(xgl + (unsigned)eA2.y * ROWB);
    const int4 viA3 = *(const int4*)(xgl + (unsigned)eA3.x * ROWB);
    const int4 vjA3 = *(const int4*)(xgl + (unsigned)eA3.y * ROWB);
    const int4 eB0 = se[lbase + 4 * 8];
    const int4 eB1 = se[lbase + 5 * 8];
    const int4 eB2 = se[lbase + 6 * 8];
    const int4 eB3 = se[lbase + 7 * 8];
    const int4 viB0 = *(const int4*)(xgl + (unsigned)eB0.x * ROWB);
    const int4 vjB0 = *(const int4*)(xgl + (unsigned)eB0.y * ROWB);
    const int4 viB1 = *(const int4*)(xgl + (unsigned)eB1.x * ROWB);
    const int4 vjB1 = *(const int4*)(xgl + (unsigned)eB1.y * ROWB);
    const int4 viB2 = *(const int4*)(xgl + (unsigned)eB2.x * ROWB);
    const int4 vjB2 = *(const int4*)(xgl + (unsigned)eB2.y * ROWB);
    const int4 viB3 = *(const int4*)(xgl + (unsigned)eB3.x * ROWB);
    const int4 vjB3 = *(const int4*)(xgl + (unsigned)eB3.y * ROWB);
    __builtin_amdgcn_sched_barrier(0);
    // ---- consume cluster ----
    fma8mix(acc, viA0, vjA0, __int_as_float(eA0.z));
    fma8mix(acc, viA1, vjA1, __int_as_float(eA1.z));
    fma8mix(acc, viA2, vjA2, __int_as_float(eA2.z));
    fma8mix(acc, viA3, vjA3, __int_as_float(eA3.z));
    fma8mix(acc, viB0, vjB0, __int_as_float(eB0.z));
    fma8mix(acc, viB1, vjB1, __int_as_float(eB1.z));
    fma8mix(acc, viB2, vjB2, __int_as_float(eB2.z));
    fma8mix(acc, viB3, vjB3, __int_as_float(eB3.z));
    __syncthreads();
  }

  // combine the 8 k-lanes sharing each column eighth (xor 8,16,32)
#pragma unroll
  for (int off = 8; off < 64; off <<= 1)
#pragma unroll
    for (int w = 0; w < 8; ++w) acc[w] += __shfl_xor(acc[w], off);

  __shared__ float red[4][GCOLS];
  if (lane < 8)
#pragma unroll
    for (int w = 0; w < 8; ++w) red[wave][lane * 8 + w] = acc[w];
  __syncthreads();
  if (tid < GCOLS) {
    const float s = red[0][tid] + red[1][tid] + red[2][tid] + red[3][tid];
    P[((size_t)g * RANKS + rank) * GCOLS + tid] = s;
  }
}

// ---------------------------------------------------------------------------
// Kernel 3: stage-1 reduce. Blocks [0,16): edge partials (g,s) sum 128 rank
// rows -> P2. Blocks [16,24): h partials, block s sums rows r%8==s -> hp2.
// ---------------------------------------------------------------------------
__global__ __launch_bounds__(256) void reduce1_kernel(
    const float* __restrict__ P, const float* __restrict__ hp,
    float* __restrict__ P2, float* __restrict__ hp2, int hrows) {
  __shared__ float red[4][GCOLS];
  __shared__ float redh[2][BDIM];
  if (blockIdx.x < S1BLK) {
    const int g  = blockIdx.x >> 3;
    const int s  = blockIdx.x & 7;
    const int rl = threadIdx.x >> 6;  // 0..3
    const int c  = threadIdx.x & 63;
    float acc = 0.f;
    for (int rr = rl; rr < RPS; rr += 4)
      acc += P[((size_t)g * RANKS + s * RPS + rr) * GCOLS + c];
    red[rl][c] = acc;
    __syncthreads();
    if (threadIdx.x < GCOLS) {
      float sum = 0.f;
      for (int r = 0; r < 4; ++r) sum += red[r][threadIdx.x];
      P2[(size_t)blockIdx.x * GCOLS + threadIdx.x] = sum;
    }
  } else {
    const int s  = blockIdx.x - S1BLK;   // 0..7
    const int b  = threadIdx.x & 127;
    const int rg = threadIdx.x >> 7;
    float acc = 0.f;
    for (int r = s + 8 * rg; r < hrows; r += 16)
      acc += hp[(size_t)r * BDIM + b];
    redh[rg][b] = acc;
    __syncthreads();
    if (threadIdx.x < BDIM)
      hp2[(size_t)s * BDIM + threadIdx.x] = redh[0][threadIdx.x] + redh[1][threadIdx.x];
  }
}

// ---------------------------------------------------------------------------
// Kernel 4: final: out[b] = sum_s hp2[s][b] + sum_s P2[(g*8+s)][c].
// ---------------------------------------------------------------------------
__global__ __launch_bounds__(128) void reduce2_kernel(
    const float* __restrict__ P2, const float* __restrict__ hp2,
    float* __restrict__ out) {
  const int b = threadIdx.x;
  const int g = b >> 6;
  const int c = b & 63;
  float acc = 0.f;
  for (int s = 0; s < 8; ++s) acc += hp2[(size_t)s * BDIM + b];
  for (int s = 0; s < 8; ++s) acc += P2[(size_t)(g * 8 + s) * GCOLS + c];
  out[b] = acc;
}

extern "C" void kernel_launch(void* const* d_in, const int* in_sizes, int n_in,
                              void* d_out, int out_size, void* d_ws, size_t ws_size,
                              hipStream_t stream) {
  const float* x  = (const float*)d_in[0];
  const float* h  = (const float*)d_in[1];
  const float* J  = (const float*)d_in[2];
  const int*   ei = (const int*)d_in[3];
  const int*   ej = (const int*)d_in[4];
  float* out = (float*)d_out;

  const int N = in_sizes[1];   // 50000
  const int E = in_sizes[2];   // 1600000

  const int tblocks = (N + 63) / 64;

  // ws layout: xTh (2*N*64 halves) | P (2048*64) | P2 (16*64) | hp (tblocks*128) | hp2 (8*128)
  __half* xTh = (__half*)d_ws;
  float* P   = (float*)(xTh + (size_t)NGROUPS * N * GCOLS);
  float* P2  = P   + (size_t)NGROUPS * RANKS * GCOLS;
  float* hp  = P2  + (size_t)S1BLK * GCOLS;
  float* hp2 = hp  + (size_t)tblocks * BDIM;

  // 1) transpose + fp16 convert + h-term partials
  transpose_h_kernel<<<tblocks, 256, 0, stream>>>(x, h, xTh, hp, N);

  // 2) edge interactions (2 groups, XCD-quad affine, 128B lines, pinned 16-deep MLP)
  edge_kernel<<<EBLK, 256, 0, stream>>>(xTh, J, ei, ej, P, E, N);

  // 3) stage-1 reduce (edge partials + h partials)
  reduce1_kernel<<<S1BLK + HBLK2, 256, 0, stream>>>(P, hp, P2, hp2, tblocks);

  // 4) final deterministic reduce (overwrites d_out)
  reduce2_kernel<<<1, BDIM, 0, stream>>>(P2, hp2, out);
}